// Round 1
// baseline (301.594 us; speedup 1.0000x reference)
//
#include <hip/hip_runtime.h>
#include <math.h>

#define NROWS 16384
#define NCOLS 1000
#define NQ    250                       // NCOLS / 4 float4s per row
#define NMAT  5
#define PAIRS (NROWS * NMAT)            // 81920 (matrix-major: p = m*NROWS + row)
#define WPB   4                         // waves per block
#define BLOCKS_A (PAIRS / WPB)          // 20480

// ---------------------------------------------------------------------------
// Kernel A: one 64-lane wave per (matrix, row). Streams the row with float4
// loads, maintains per-lane top-2, butterfly-merges across the wave.
// Also produces per-block max over matrices 0..3 (for max_preds).
// ---------------------------------------------------------------------------
__global__ __launch_bounds__(256) void margins_kernel(
    const float* __restrict__ o0, const float* __restrict__ o1,
    const float* __restrict__ o2, const float* __restrict__ o3,
    const float* __restrict__ o4, const int* __restrict__ targets,
    float* __restrict__ margins, float* __restrict__ blockmax)
{
    const int wave = threadIdx.x >> 6;
    const int lane = threadIdx.x & 63;
    const int p    = blockIdx.x * WPB + wave;
    const int m    = p >> 14;            // p / NROWS (NROWS = 2^14)
    const int row  = p & (NROWS - 1);

    const float* mat = (m == 0) ? o0 : (m == 1) ? o1 : (m == 2) ? o2
                       : (m == 3) ? o3 : o4;
    const float*  rowp = mat + (size_t)row * NCOLS;   // row*4000 B, 16B aligned
    const float4* base = (const float4*)rowp;

    // Issue all loads up front (ILP); 250 float4s -> lanes 0..57 take a 4th.
    float4 v0 = base[lane];
    float4 v1 = base[lane + 64];
    float4 v2 = base[lane + 128];
    float4 v3 = make_float4(-INFINITY, -INFINITY, -INFINITY, -INFINITY);
    if (lane < (NQ - 192)) v3 = base[lane + 192];

    float t1 = -INFINITY, t2 = -INFINITY;
    // branch-free top-2 update: t2 = max(t2, min(t1_old, x)); t1 = max(t1_old, x)
#define UPD(x) { float _mn = fminf(t1, (x)); t1 = fmaxf(t1, (x)); t2 = fmaxf(t2, _mn); }
    UPD(v0.x) UPD(v0.y) UPD(v0.z) UPD(v0.w)
    UPD(v1.x) UPD(v1.y) UPD(v1.z) UPD(v1.w)
    UPD(v2.x) UPD(v2.y) UPD(v2.z) UPD(v2.w)
    UPD(v3.x) UPD(v3.y) UPD(v3.z) UPD(v3.w)
#undef UPD

    // Butterfly merge of (top1, top2) pairs across the 64-lane wave.
    #pragma unroll
    for (int off = 32; off > 0; off >>= 1) {
        float a1 = __shfl_xor(t1, off);
        float a2 = __shfl_xor(t2, off);
        float mn = fminf(t1, a1);
        t1 = fmaxf(t1, a1);
        t2 = fmaxf(fmaxf(t2, a2), mn);
    }
    // All lanes now hold the wave-wide (t1, t2).

    if (lane == 0) {
        const int   t   = targets[row];
        const float tgt = rowp[t];
        // margin = top1 - top2 iff target attains the max (exact fp compare,
        // same semantics as reference's tgt_logit == top2[:,0])
        const float margin = (tgt == t1) ? (t1 - t2) : 0.0f;
        margins[row * NMAT + m] = margin;
    }

    // Block max over matrices 0..3 only (mimic excluded from max_preds).
    __shared__ float smax[WPB];
    if (lane == 0) smax[wave] = (m < 4) ? t1 : -INFINITY;
    __syncthreads();
    if (threadIdx.x == 0) {
        blockmax[blockIdx.x] =
            fmaxf(fmaxf(smax[0], smax[1]), fmaxf(smax[2], smax[3]));
    }
}

// ---------------------------------------------------------------------------
// Kernel B: per-row softmax(margins / 2) -> d_out[1..]; block 0 also reduces
// the 20480 per-block maxima -> d_out[0].
// ---------------------------------------------------------------------------
__global__ __launch_bounds__(256) void softmax_kernel(
    const float* __restrict__ margins, const float* __restrict__ blockmax,
    float* __restrict__ out)
{
    const int row = blockIdx.x * 256 + threadIdx.x;   // 64 blocks x 256 = 16384

    float mg[NMAT];
    #pragma unroll
    for (int j = 0; j < NMAT; ++j) mg[j] = margins[row * NMAT + j];

    float mx = mg[0];
    #pragma unroll
    for (int j = 1; j < NMAT; ++j) mx = fmaxf(mx, mg[j]);

    float e[NMAT];
    float s = 0.0f;
    #pragma unroll
    for (int j = 0; j < NMAT; ++j) { e[j] = expf((mg[j] - mx) * 0.5f); s += e[j]; }
    const float inv = 1.0f / s;
    #pragma unroll
    for (int j = 0; j < NMAT; ++j) out[1 + row * NMAT + j] = e[j] * inv;

    if (blockIdx.x == 0) {
        __shared__ float red[256];
        float mm = -INFINITY;
        for (int k = threadIdx.x; k < BLOCKS_A; k += 256)
            mm = fmaxf(mm, blockmax[k]);
        red[threadIdx.x] = mm;
        __syncthreads();
        #pragma unroll
        for (int s2 = 128; s2 > 0; s2 >>= 1) {
            if (threadIdx.x < s2)
                red[threadIdx.x] = fmaxf(red[threadIdx.x], red[threadIdx.x + s2]);
            __syncthreads();
        }
        if (threadIdx.x == 0) out[0] = red[0];
    }
}

extern "C" void kernel_launch(void* const* d_in, const int* in_sizes, int n_in,
                              void* d_out, int out_size, void* d_ws, size_t ws_size,
                              hipStream_t stream) {
    const float* o0 = (const float*)d_in[0];
    const float* o1 = (const float*)d_in[1];
    const float* o2 = (const float*)d_in[2];
    const float* o3 = (const float*)d_in[3];
    const float* o4 = (const float*)d_in[4];
    const int*   tg = (const int*)d_in[5];
    float* out = (float*)d_out;

    float* margins  = (float*)d_ws;           // PAIRS floats   (327,680 B)
    float* blockmax = margins + PAIRS;        // BLOCKS_A floats (81,920 B)

    margins_kernel<<<BLOCKS_A, 256, 0, stream>>>(o0, o1, o2, o3, o4, tg,
                                                 margins, blockmax);
    softmax_kernel<<<64, 256, 0, stream>>>(margins, blockmax, out);
}

// Round 2
// 293.596 us; speedup vs baseline: 1.0272x; 1.0272x over previous
//
#include <hip/hip_runtime.h>
#include <math.h>

#define NROWS 16384
#define NCOLS 1000
#define NMAT  5
#define WPB   4                         // waves (rows) per block
#define BLOCKS_A (NROWS / WPB)          // 4096

// ---------------------------------------------------------------------------
// Fused kernel: one 64-lane wave per row, covering ALL 5 matrices.
// 20 float4 loads issued up-front (5x memory-level parallelism vs R1),
// 5 interleaved top-2 butterflies, per-row softmax fused in lane 0.
// Also produces per-block max over matrices 0..3 -> blockmax[].
// ---------------------------------------------------------------------------
__global__ __launch_bounds__(256) void fused_kernel(
    const float* __restrict__ o0, const float* __restrict__ o1,
    const float* __restrict__ o2, const float* __restrict__ o3,
    const float* __restrict__ o4, const int* __restrict__ targets,
    float* __restrict__ out, float* __restrict__ blockmax)
{
    const int wave = threadIdx.x >> 6;
    const int lane = threadIdx.x & 63;
    const int row  = blockIdx.x * WPB + wave;

    const float* rows[NMAT];
    rows[0] = o0 + (size_t)row * NCOLS;
    rows[1] = o1 + (size_t)row * NCOLS;
    rows[2] = o2 + (size_t)row * NCOLS;
    rows[3] = o3 + (size_t)row * NCOLS;
    rows[4] = o4 + (size_t)row * NCOLS;

    // Issue all 20 loads up front: 20 KB in flight per wave.
    float4 v[NMAT][4];
    #pragma unroll
    for (int m = 0; m < NMAT; ++m) {
        const float4* b = (const float4*)rows[m];
        v[m][0] = b[lane];
        v[m][1] = b[lane + 64];
        v[m][2] = b[lane + 128];
        v[m][3] = make_float4(-INFINITY, -INFINITY, -INFINITY, -INFINITY);
    }
    if (lane < 58) {                     // 250 float4 per row; lanes 0..57 take a 4th
        #pragma unroll
        for (int m = 0; m < NMAT; ++m)
            v[m][3] = ((const float4*)rows[m])[lane + 192];
    }

    // Per-lane top-2 (branch-free; duplicates of the max handled correctly).
    float t1[NMAT], t2[NMAT];
#define UPD(m, x) { float _mn = fminf(t1[m], (x)); t1[m] = fmaxf(t1[m], (x)); \
                    t2[m] = fmaxf(t2[m], _mn); }
    #pragma unroll
    for (int m = 0; m < NMAT; ++m) {
        t1[m] = -INFINITY; t2[m] = -INFINITY;
        #pragma unroll
        for (int q = 0; q < 4; ++q) {
            UPD(m, v[m][q].x) UPD(m, v[m][q].y)
            UPD(m, v[m][q].z) UPD(m, v[m][q].w)
        }
    }
#undef UPD

    // 6-step butterfly, all 5 matrices interleaved (10 independent shuffles
    // per step so ds-latency overlaps).
    #pragma unroll
    for (int off = 32; off > 0; off >>= 1) {
        float a1[NMAT], a2[NMAT];
        #pragma unroll
        for (int m = 0; m < NMAT; ++m) {
            a1[m] = __shfl_xor(t1[m], off);
            a2[m] = __shfl_xor(t2[m], off);
        }
        #pragma unroll
        for (int m = 0; m < NMAT; ++m) {
            float mn = fminf(t1[m], a1[m]);
            t1[m] = fmaxf(t1[m], a1[m]);
            t2[m] = fmaxf(fmaxf(t2[m], a2[m]), mn);
        }
    }

    // Fused tail: margins + softmax, once per row (lane 0).
    if (lane == 0) {
        const int t = targets[row];
        float mg[NMAT];
        #pragma unroll
        for (int m = 0; m < NMAT; ++m) {
            const float tgt = rows[m][t];          // L1-hot, 5 independent loads
            mg[m] = (tgt == t1[m]) ? (t1[m] - t2[m]) : 0.0f;
        }
        float mx = mg[0];
        #pragma unroll
        for (int m = 1; m < NMAT; ++m) mx = fmaxf(mx, mg[m]);
        float e[NMAT], s = 0.0f;
        #pragma unroll
        for (int m = 0; m < NMAT; ++m) { e[m] = __expf((mg[m] - mx) * 0.5f); s += e[m]; }
        const float inv = 1.0f / s;
        #pragma unroll
        for (int m = 0; m < NMAT; ++m) out[1 + row * NMAT + m] = e[m] * inv;
    }

    // Per-block max over matrices 0..3 (mimic excluded from max_preds).
    __shared__ float smax[WPB];
    if (lane == 0)
        smax[wave] = fmaxf(fmaxf(t1[0], t1[1]), fmaxf(t1[2], t1[3]));
    __syncthreads();
    if (threadIdx.x == 0)
        blockmax[blockIdx.x] =
            fmaxf(fmaxf(smax[0], smax[1]), fmaxf(smax[2], smax[3]));
}

// ---------------------------------------------------------------------------
// Tiny reduce: 4096 block maxima -> out[0].
// ---------------------------------------------------------------------------
__global__ __launch_bounds__(256) void reduce_kernel(
    const float* __restrict__ blockmax, float* __restrict__ out)
{
    __shared__ float red[256];
    float mm = -INFINITY;
    for (int k = threadIdx.x; k < BLOCKS_A; k += 256)
        mm = fmaxf(mm, blockmax[k]);
    red[threadIdx.x] = mm;
    __syncthreads();
    #pragma unroll
    for (int s = 128; s > 0; s >>= 1) {
        if (threadIdx.x < s)
            red[threadIdx.x] = fmaxf(red[threadIdx.x], red[threadIdx.x + s]);
        __syncthreads();
    }
    if (threadIdx.x == 0) out[0] = red[0];
}

extern "C" void kernel_launch(void* const* d_in, const int* in_sizes, int n_in,
                              void* d_out, int out_size, void* d_ws, size_t ws_size,
                              hipStream_t stream) {
    const float* o0 = (const float*)d_in[0];
    const float* o1 = (const float*)d_in[1];
    const float* o2 = (const float*)d_in[2];
    const float* o3 = (const float*)d_in[3];
    const float* o4 = (const float*)d_in[4];
    const int*   tg = (const int*)d_in[5];
    float* out = (float*)d_out;

    float* blockmax = (float*)d_ws;              // BLOCKS_A floats (16 KB)

    fused_kernel<<<BLOCKS_A, 256, 0, stream>>>(o0, o1, o2, o3, o4, tg,
                                               out, blockmax);
    reduce_kernel<<<1, 256, 0, stream>>>(blockmax, out);
}